// Round 6
// baseline (280.741 us; speedup 1.0000x reference)
//
#include <hip/hip_runtime.h>
#include <hip/hip_bf16.h>

using bf16 = __hip_bfloat16;

#define C1 1.44269504f   // log2(e)
#define C2 2.88539008f   // 2*log2(e)

__device__ __forceinline__ float fexp2(float x) { return __builtin_amdgcn_exp2f(x); }
__device__ __forceinline__ float frcp(float x)  { return __builtin_amdgcn_rcpf(x); }
// sigmoid(v) with x = C1*v applied upstream
__device__ __forceinline__ float sigm2(float x) { return frcp(1.f + fexp2(-x)); }
// tanh(y) with x = C2*y applied upstream
__device__ __forceinline__ float tanh2(float x) { return 1.f - 2.f * frcp(1.f + fexp2(x)); }

__device__ __forceinline__ unsigned int f2bfbits(float f) {  // RNE float->bf16 bits
    union { float f; unsigned int u; } c; c.f = f;
    return (c.u + 0x7fffu + ((c.u >> 16) & 1u)) >> 16;
}

// gi layout: [k][b][12] of uint2 {lo = r|z<<16, hi = n} (bf16 bits, pre-scaled C1/C1/C2)
#define KSTR 12288   // uint2 per k-slice (1024*12)
// ws: gi @0 (15,728,640 B) | pegi float4[160][12] @15,728,640 (30,720 B)
//     Wcg float[160][156] @15,759,360 (99,840 B)  => 15.86 MB
#define OFF_PEGI 15728640
#define OFF_WC   15759360

// ---------------------------------------------------------------
// Kernel 1: encoder + input-gate precompute. grid (4,160) x 256.
// LDS-staged gi stores (padded stride-13) for coalesced global writes.
// ---------------------------------------------------------------
__global__ __launch_bounds__(256) void k_encode(
    const float* __restrict__ x, const float* __restrict__ encW, const float* __restrict__ encb,
    const float* __restrict__ Wih, const float* __restrict__ bih, const float* __restrict__ bhh,
    uint2* __restrict__ gi, float4* __restrict__ pegi)
{
    const int k = blockIdx.y, t = threadIdx.x;
    const int b = blockIdx.x * 256 + t;

    __shared__ float sW[144], sbm[12], sWih[432], sbih[36], spet[12];
    __shared__ uint2 st[256 * 13];          // 26 KB staging, stride 13
    if (t < 144) sW[t]  = encW[k * 144 + t];
    if (t < 12)  sbm[t] = encb[k * 12 + t];
    for (int i = t; i < 432; i += 256) sWih[i] = Wih[i];
    if (t < 36)  sbih[t] = bih[t] + (t < 24 ? bhh[t] : 0.f);
    if (t < 12) {
        int m = t >> 1;
        float div = __expf((float)(2 * m) * (-0.7675283643313489f)); // -ln(10000)/12
        float ang = (float)k * div;
        spet[t] = ((t & 1) ? cosf(ang) : sinf(ang)) + sinf((float)k);
    }
    __syncthreads();
    if (t < 12 && blockIdx.x == 0) {
        float sr = 0.f, sz = 0.f, sn = 0.f;
        #pragma unroll
        for (int o = 0; o < 12; o++) {
            sr = fmaf(spet[o], sWih[t * 12 + o], sr);
            sz = fmaf(spet[o], sWih[(12 + t) * 12 + o], sz);
            sn = fmaf(spet[o], sWih[(24 + t) * 12 + o], sn);
        }
        pegi[k * 12 + t] = make_float4(C1 * sr, C1 * sz, C2 * sn, 0.f);
    }

    const float4* xp = reinterpret_cast<const float4*>(x + (size_t)b * 1920 + k * 12);
    float4 a0 = xp[0], a1 = xp[1], a2 = xp[2];
    float xv[12] = {a0.x,a0.y,a0.z,a0.w, a1.x,a1.y,a1.z,a1.w, a2.x,a2.y,a2.z,a2.w};

    float xs[12];
    #pragma unroll
    for (int o = 0; o < 12; o++) {
        float s = sbm[o];
        #pragma unroll
        for (int i = 0; i < 12; i++) s = fmaf(xv[i], sW[i * 12 + o], s);
        xs[o] = fmaxf(s, 0.f);
    }

    #pragma unroll
    for (int j = 0; j < 12; j++) {
        float sr = sbih[j], sz = sbih[12 + j], sn = sbih[24 + j];
        #pragma unroll
        for (int o = 0; o < 12; o++) {
            sr = fmaf(xs[o], sWih[j * 12 + o], sr);
            sz = fmaf(xs[o], sWih[(12 + j) * 12 + o], sz);
            sn = fmaf(xs[o], sWih[(24 + j) * 12 + o], sn);
        }
        st[t * 13 + j] = make_uint2(f2bfbits(C1 * sr) | (f2bfbits(C1 * sz) << 16),
                                    f2bfbits(C2 * sn));
    }
    __syncthreads();
    uint2* gbase = gi + (size_t)k * KSTR + (size_t)blockIdx.x * 3072;
    for (int i = t; i < 3072; i += 256) {
        int bl = i / 12;
        gbase[i] = st[bl * 13 + (i - bl * 12)];
    }
}

// ---------------------------------------------------------------
// GRU helpers
// ---------------------------------------------------------------
__device__ __forceinline__ float gru_gates(float gr, float gz, float gn,
                                           const float* wr, const float* wz, const float* wn,
                                           float bn, const float* h, float hself)
{
    float hr = 0.f, hz = 0.f, hn = bn;
    #pragma unroll
    for (int d = 0; d < 12; d++) {
        hr = fmaf(wr[d], h[d], hr);
        hz = fmaf(wz[d], h[d], hz);
        hn = fmaf(wn[d], h[d], hn);
    }
    float r = sigm2(gr + hr);
    float z = sigm2(gz + hz);
    float n = tanh2(fmaf(r, hn, gn));
    return fmaf(z, hself - n, n);      // (1-z)*n + z*h
}

__device__ __forceinline__ void bcast12(float* h, float hj, const int* ba)
{
    int v = __float_as_int(hj);
    #pragma unroll
    for (int d = 0; d < 12; d++)
        h[d] = __int_as_float(__builtin_amdgcn_ds_bpermute(ba[d], v));
}

// ---------------------------------------------------------------
// Kernel 2: two GRU passes, 2-way chain-interleaved.
// 128 blocks x 64. 8 chains/wave: groups A,B of 4 spatial chains
// (16 lanes each); A's latency hidden by B's issue and vice versa.
// pegi in LDS; gi prefetch depth 4 per group.
// ---------------------------------------------------------------
__global__ __launch_bounds__(64) void k_recur(
    const float* __restrict__ Whh, const float* __restrict__ bhh,
    const uint2* __restrict__ gi, const float4* __restrict__ pegi,
    float* __restrict__ hout)
{
    __shared__ float4 spe[1920];            // [k][ju], 30 KB
    const int lane = threadIdx.x;
    for (int i = lane; i < 1920; i += 64) spe[i] = pegi[i];

    const int g = lane >> 4, j = lane & 15;
    const int ju = (j < 12) ? j : 0;
    const int bA = blockIdx.x * 8 + g;
    const int bB = bA + 4;

    int ba[12];
    #pragma unroll
    for (int d = 0; d < 12; d++) ba[d] = ((lane & ~15) + d) << 2;

    float wr[12], wz[12], wn[12];
    #pragma unroll
    for (int d = 0; d < 12; d++) {
        wr[d] = C1 * Whh[ju * 12 + d];
        wz[d] = C1 * Whh[(12 + ju) * 12 + d];
        wn[d] = C2 * Whh[(24 + ju) * 12 + d];
    }
    const float bn = C2 * bhh[24 + ju];
    __syncthreads();

    const uint2* gpA = gi + (size_t)bA * 12 + ju;
    const uint2* gpB = gi + (size_t)bB * 12 + ju;

    float hA[12], hB[12], hsA = 0.f, hsB = 0.f;
    #pragma unroll
    for (int d = 0; d < 12; d++) { hA[d] = 0.f; hB[d] = 0.f; }

    uint2 bufA[4], bufB[4];
    #pragma unroll
    for (int i = 0; i < 4; i++) { bufA[i] = gpA[(size_t)i * KSTR]; bufB[i] = gpB[(size_t)i * KSTR]; }

    // ---- GRU1 (only final h needed) ----
    for (int ko = 0; ko < 160; ko += 4) {
        #pragma unroll
        for (int i = 0; i < 4; i++) {
            const int k = ko + i;
            const int kp = (k + 4 > 159) ? 159 : k + 4;
            // group A
            float grA = __int_as_float((int)(bufA[i].x << 16));
            float gzA = __int_as_float((int)(bufA[i].x & 0xffff0000u));
            float gnA = __int_as_float((int)(bufA[i].y << 16));
            bufA[i] = gpA[(size_t)kp * KSTR];
            float hjA = gru_gates(grA, gzA, gnA, wr, wz, wn, bn, hA, hsA);
            hsA = hjA;
            bcast12(hA, hjA, ba);
            // group B
            float grB = __int_as_float((int)(bufB[i].x << 16));
            float gzB = __int_as_float((int)(bufB[i].x & 0xffff0000u));
            float gnB = __int_as_float((int)(bufB[i].y << 16));
            bufB[i] = gpB[(size_t)kp * KSTR];
            float hjB = gru_gates(grB, gzB, gnB, wr, wz, wn, bn, hB, hsB);
            hsB = hjB;
            bcast12(hB, hjB, ba);
        }
    }

    // ---- GRU2 (emit h every step); gi2 = gi1 + pegi[k] ----
    float4 spb[4];
    #pragma unroll
    for (int i = 0; i < 4; i++) {
        bufA[i] = gpA[(size_t)i * KSTR];
        bufB[i] = gpB[(size_t)i * KSTR];
        spb[i]  = spe[i * 12 + ju];
    }
    float* hoA = hout + (size_t)bA * 1920;
    float* hoB = hout + (size_t)bB * 1920;
    for (int ko = 0; ko < 160; ko += 4) {
        #pragma unroll
        for (int i = 0; i < 4; i++) {
            const int k = ko + i;
            const int kp = (k + 4 > 159) ? 159 : k + 4;
            float4 sp = spb[i];
            spb[i] = spe[kp * 12 + ju];
            // group A
            float grA = __int_as_float((int)(bufA[i].x << 16))        + sp.x;
            float gzA = __int_as_float((int)(bufA[i].x & 0xffff0000u)) + sp.y;
            float gnA = __int_as_float((int)(bufA[i].y << 16))        + sp.z;
            bufA[i] = gpA[(size_t)kp * KSTR];
            float hjA = gru_gates(grA, gzA, gnA, wr, wz, wn, bn, hA, hsA);
            hsA = hjA;
            if (j < 12) hoA[k * 12 + j] = hjA;
            bcast12(hA, hjA, ba);
            // group B
            float grB = __int_as_float((int)(bufB[i].x << 16))        + sp.x;
            float gzB = __int_as_float((int)(bufB[i].x & 0xffff0000u)) + sp.y;
            float gnB = __int_as_float((int)(bufB[i].y << 16))        + sp.z;
            bufB[i] = gpB[(size_t)kp * KSTR];
            float hjB = gru_gates(grB, gzB, gnB, wr, wz, wn, bn, hB, hsB);
            hsB = hjB;
            if (j < 12) hoB[k * 12 + j] = hjB;
            bcast12(hB, hjB, ba);
        }
    }
}

// ---------------------------------------------------------------
// Kernel 3: fold Wc = W1@W2, bc = b1@W2+b2 per k. LDS-staged W2.
// grid 160 x 256.
// ---------------------------------------------------------------
__global__ __launch_bounds__(256) void k_fold(
    const float* __restrict__ W1, const float* __restrict__ b1,
    const float* __restrict__ W2, const float* __restrict__ b2,
    float* __restrict__ Wcg)
{
    const int k = blockIdx.x, t = threadIdx.x;
    __shared__ float sB[12288];   // W2[k], [h][12]
    __shared__ float sb1[1024];
    {
        const float4* w2p = reinterpret_cast<const float4*>(W2 + (size_t)k * 12288);
        float4* sB4 = reinterpret_cast<float4*>(sB);
        for (int i = t; i < 3072; i += 256) sB4[i] = w2p[i];
        const float4* b1p = reinterpret_cast<const float4*>(b1 + (size_t)k * 1024);
        float4* sb14 = reinterpret_cast<float4*>(sb1);
        if (t < 256) sb14[t] = b1p[t];
    }
    __syncthreads();
    if (t >= 156) return;
    const int o = (t < 144) ? (t % 12) : (t - 144);
    float s0 = 0.f, s1 = 0.f, s2 = 0.f, s3 = 0.f;
    if (t < 144) {
        const float4* va4 = reinterpret_cast<const float4*>(W1 + (size_t)k * 12288 + (size_t)(t / 12) * 1024);
        #pragma unroll 4
        for (int q = 0; q < 256; q++) {
            float4 a = va4[q];
            const float* bq = sB + q * 48 + o;
            s0 = fmaf(a.x, bq[0],  s0);
            s1 = fmaf(a.y, bq[12], s1);
            s2 = fmaf(a.z, bq[24], s2);
            s3 = fmaf(a.w, bq[36], s3);
        }
    } else {
        #pragma unroll 4
        for (int hh = 0; hh < 1024; hh += 4) {
            const float* bq = sB + hh * 12 + o;
            s0 = fmaf(sb1[hh],     bq[0],  s0);
            s1 = fmaf(sb1[hh + 1], bq[12], s1);
            s2 = fmaf(sb1[hh + 2], bq[24], s2);
            s3 = fmaf(sb1[hh + 3], bq[36], s3);
        }
    }
    float s = (s0 + s1) + (s2 + s3);
    if (t >= 144) s += b2[k * 12 + o];
    Wcg[k * 156 + t] = s;
}

// ---------------------------------------------------------------
// Kernel 4: apply, in-place on d_out. grid 160 x 256.
// ---------------------------------------------------------------
__global__ __launch_bounds__(256) void k_apply(
    const float* __restrict__ Wcg, float* __restrict__ out)
{
    const int k = blockIdx.x, t = threadIdx.x;
    __shared__ float sw[156];
    if (t < 156) sw[t] = Wcg[k * 156 + t];
    __syncthreads();

    for (int bb = t; bb < 1024; bb += 256) {
        float* hp = out + (size_t)bb * 1920 + k * 12;
        float4* h4 = reinterpret_cast<float4*>(hp);
        float4 a0 = h4[0], a1 = h4[1], a2 = h4[2];
        float hv[12] = {a0.x,a0.y,a0.z,a0.w, a1.x,a1.y,a1.z,a1.w, a2.x,a2.y,a2.z,a2.w};
        float ov[12];
        #pragma unroll
        for (int o = 0; o < 12; o++) {
            float s = sw[144 + o];
            #pragma unroll
            for (int d = 0; d < 12; d++) s = fmaf(hv[d], sw[d * 12 + o], s);
            ov[o] = s;
        }
        h4[0] = make_float4(ov[0], ov[1], ov[2],  ov[3]);
        h4[1] = make_float4(ov[4], ov[5], ov[6],  ov[7]);
        h4[2] = make_float4(ov[8], ov[9], ov[10], ov[11]);
    }
}

// ---------------------------------------------------------------
extern "C" void kernel_launch(void* const* d_in, const int* in_sizes, int n_in,
                              void* d_out, int out_size, void* d_ws, size_t ws_size,
                              hipStream_t stream)
{
    const float* x    = (const float*)d_in[0];
    const float* encW = (const float*)d_in[1];
    const float* encb = (const float*)d_in[2];
    const float* Wih  = (const float*)d_in[3];
    const float* Whh  = (const float*)d_in[4];
    const float* bih  = (const float*)d_in[5];
    const float* bhh  = (const float*)d_in[6];
    const float* W1   = (const float*)d_in[7];
    const float* b1   = (const float*)d_in[8];
    const float* W2   = (const float*)d_in[9];
    const float* b2   = (const float*)d_in[10];
    float* out = (float*)d_out;

    char* ws = (char*)d_ws;
    uint2*  gi   = (uint2*)(ws);
    float4* pegi = (float4*)(ws + OFF_PEGI);
    float*  Wcg  = (float*)(ws + OFF_WC);

    k_encode<<<dim3(4, 160), 256, 0, stream>>>(x, encW, encb, Wih, bih, bhh, gi, pegi);
    k_fold  <<<dim3(160),    256, 0, stream>>>(W1, b1, W2, b2, Wcg);
    k_recur <<<dim3(128),    64,  0, stream>>>(Whh, bhh, gi, pegi, out);
    k_apply <<<dim3(160),    256, 0, stream>>>(Wcg, out);
}

// Round 7
// 202.727 us; speedup vs baseline: 1.3848x; 1.3848x over previous
//
#include <hip/hip_runtime.h>
#include <hip/hip_bf16.h>

using bf16 = __hip_bfloat16;

#define C1 1.44269504f   // log2(e)
#define C2 2.88539008f   // 2*log2(e)

__device__ __forceinline__ float fexp2(float x) { return __builtin_amdgcn_exp2f(x); }
__device__ __forceinline__ float frcp(float x)  { return __builtin_amdgcn_rcpf(x); }

__device__ __forceinline__ unsigned int f2bfbits(float f) {  // RNE float->bf16 bits
    union { float f; unsigned int u; } c; c.f = f;
    return (c.u + 0x7fffu + ((c.u >> 16) & 1u)) >> 16;
}

// gi layout: [k][b][12] of uint2 {lo = r|z<<16, hi = n} (bf16 bits, pre-scaled C1/C1/C2)
#define KSTR 12288   // uint2 per k-slice (1024*12)
// ws: gi @0 (15,728,640 B) | pegi float4[160][12] @15,728,640 (30,720 B)
//     Wcg float[160][156] @15,759,360 (99,840 B)  => 15.86 MB
#define OFF_PEGI 15728640
#define OFF_WC   15759360

// ---------------------------------------------------------------
// Kernel 1: encoder + input-gate precompute. grid (4,160) x 256.
// (unchanged from r5 — proven)
// ---------------------------------------------------------------
__global__ __launch_bounds__(256) void k_encode(
    const float* __restrict__ x, const float* __restrict__ encW, const float* __restrict__ encb,
    const float* __restrict__ Wih, const float* __restrict__ bih, const float* __restrict__ bhh,
    uint2* __restrict__ gi, float4* __restrict__ pegi)
{
    const int k = blockIdx.y, t = threadIdx.x;
    const int b = blockIdx.x * 256 + t;

    __shared__ float sW[144], sbm[12], sWih[432], sbih[36], spet[12];
    __shared__ uint2 st[256 * 13];          // 26 KB staging, stride 13
    if (t < 144) sW[t]  = encW[k * 144 + t];
    if (t < 12)  sbm[t] = encb[k * 12 + t];
    for (int i = t; i < 432; i += 256) sWih[i] = Wih[i];
    if (t < 36)  sbih[t] = bih[t] + (t < 24 ? bhh[t] : 0.f);
    if (t < 12) {
        int m = t >> 1;
        float div = __expf((float)(2 * m) * (-0.7675283643313489f)); // -ln(10000)/12
        float ang = (float)k * div;
        spet[t] = ((t & 1) ? cosf(ang) : sinf(ang)) + sinf((float)k);
    }
    __syncthreads();
    if (t < 12 && blockIdx.x == 0) {
        float sr = 0.f, sz = 0.f, sn = 0.f;
        #pragma unroll
        for (int o = 0; o < 12; o++) {
            sr = fmaf(spet[o], sWih[t * 12 + o], sr);
            sz = fmaf(spet[o], sWih[(12 + t) * 12 + o], sz);
            sn = fmaf(spet[o], sWih[(24 + t) * 12 + o], sn);
        }
        pegi[k * 12 + t] = make_float4(C1 * sr, C1 * sz, C2 * sn, 0.f);
    }

    const float4* xp = reinterpret_cast<const float4*>(x + (size_t)b * 1920 + k * 12);
    float4 a0 = xp[0], a1 = xp[1], a2 = xp[2];
    float xv[12] = {a0.x,a0.y,a0.z,a0.w, a1.x,a1.y,a1.z,a1.w, a2.x,a2.y,a2.z,a2.w};

    float xs[12];
    #pragma unroll
    for (int o = 0; o < 12; o++) {
        float s = sbm[o];
        #pragma unroll
        for (int i = 0; i < 12; i++) s = fmaf(xv[i], sW[i * 12 + o], s);
        xs[o] = fmaxf(s, 0.f);
    }

    #pragma unroll
    for (int j = 0; j < 12; j++) {
        float sr = sbih[j], sz = sbih[12 + j], sn = sbih[24 + j];
        #pragma unroll
        for (int o = 0; o < 12; o++) {
            sr = fmaf(xs[o], sWih[j * 12 + o], sr);
            sz = fmaf(xs[o], sWih[(12 + j) * 12 + o], sz);
            sn = fmaf(xs[o], sWih[(24 + j) * 12 + o], sn);
        }
        st[t * 13 + j] = make_uint2(f2bfbits(C1 * sr) | (f2bfbits(C1 * sz) << 16),
                                    f2bfbits(C2 * sn));
    }
    __syncthreads();
    uint2* gbase = gi + (size_t)k * KSTR + (size_t)blockIdx.x * 3072;
    for (int i = t; i < 3072; i += 256) {
        int bl = i / 12;
        gbase[i] = st[bl * 13 + (i - bl * 12)];
    }
}

// ---------------------------------------------------------------
// Kernel 2: the two GRU passes — SGPR-h design.
// ONE chain per wave (1024 blocks x 64). Lane j (<12) owns hidden
// unit j. Full h vector lives in wave-uniform regs via v_readlane
// (no LDS, no bpermute on the critical chain). Depth-8 gi prefetch.
// ---------------------------------------------------------------
__global__ __launch_bounds__(64) void k_recur(
    const float* __restrict__ Whh, const float* __restrict__ bhh,
    const uint2* __restrict__ gi, const float4* __restrict__ pegi,
    float* __restrict__ hout)
{
    const int lane = threadIdx.x;
    const int ju = (lane < 12) ? lane : 11;
    const int b = blockIdx.x;

    float wr[12], wz[12], wn[12];
    #pragma unroll
    for (int d = 0; d < 12; d++) {
        wr[d] = C1 * Whh[ju * 12 + d];
        wz[d] = C1 * Whh[(12 + ju) * 12 + d];
        wn[d] = C2 * Whh[(24 + ju) * 12 + d];
    }
    const float bn = C2 * bhh[24 + ju];

    const uint2* gp = gi + (size_t)b * 12 + ju;

    float hs[12];                       // wave-uniform (SGPR) broadcast h
    #pragma unroll
    for (int d = 0; d < 12; d++) hs[d] = 0.f;
    float hself = 0.f, p = 1.f;         // p = 1 - hself

    uint2 buf[8];
    #pragma unroll
    for (int i = 0; i < 8; i++) buf[i] = gp[(size_t)i * KSTR];

    // ---- GRU1 (only final h needed) ----
    for (int ko = 0; ko < 160; ko += 8) {
        #pragma unroll
        for (int i = 0; i < 8; i++) {
            const int k = ko + i;
            const int kp = (k + 8 > 159) ? 159 : k + 8;
            float hr = __int_as_float((int)(buf[i].x << 16));         // gr
            float hz = __int_as_float((int)(buf[i].x & 0xffff0000u)); // gz
            float gn = __int_as_float((int)(buf[i].y << 16));
            buf[i] = gp[(size_t)kp * KSTR];
            float hn = bn;
            #pragma unroll
            for (int d = 0; d < 12; d++) {
                hr = fmaf(wr[d], hs[d], hr);
                hz = fmaf(wz[d], hs[d], hz);
                hn = fmaf(wn[d], hs[d], hn);
            }
            float w = frcp(1.f + fexp2(hz));        // 1 - z
            float r = frcp(1.f + fexp2(-hr));
            float t = fmaf(r, hn, gn);
            float e = frcp(1.f + fexp2(t));         // n = 1 - 2e
            float hj = fmaf(w, fmaf(-2.f, e, p), hself); // h + w*((1-h) - 2e)
            hself = hj; p = 1.f - hj;
            int hv = __float_as_int(hj);
            #pragma unroll
            for (int d = 0; d < 12; d++)
                hs[d] = __int_as_float(__builtin_amdgcn_readlane(hv, d));
        }
    }

    // ---- GRU2 (emit h every step); gi2 = gi1 + pegi[k] ----
    const float4* pp = pegi + ju;
    float4 pb[8];
    #pragma unroll
    for (int i = 0; i < 8; i++) {
        buf[i] = gp[(size_t)i * KSTR];
        pb[i]  = pp[i * 12];
    }
    float* ho = hout + (size_t)b * 1920;            // [b][k][12]
    for (int ko = 0; ko < 160; ko += 8) {
        #pragma unroll
        for (int i = 0; i < 8; i++) {
            const int k = ko + i;
            const int kp = (k + 8 > 159) ? 159 : k + 8;
            float hr = __int_as_float((int)(buf[i].x << 16))         + pb[i].x;
            float hz = __int_as_float((int)(buf[i].x & 0xffff0000u)) + pb[i].y;
            float gn = __int_as_float((int)(buf[i].y << 16))         + pb[i].z;
            buf[i] = gp[(size_t)kp * KSTR];
            pb[i]  = pp[kp * 12];
            float hn = bn;
            #pragma unroll
            for (int d = 0; d < 12; d++) {
                hr = fmaf(wr[d], hs[d], hr);
                hz = fmaf(wz[d], hs[d], hz);
                hn = fmaf(wn[d], hs[d], hn);
            }
            float w = frcp(1.f + fexp2(hz));
            float r = frcp(1.f + fexp2(-hr));
            float t = fmaf(r, hn, gn);
            float e = frcp(1.f + fexp2(t));
            float hj = fmaf(w, fmaf(-2.f, e, p), hself);
            hself = hj; p = 1.f - hj;
            if (lane < 12) ho[k * 12 + lane] = hj;
            int hv = __float_as_int(hj);
            #pragma unroll
            for (int d = 0; d < 12; d++)
                hs[d] = __int_as_float(__builtin_amdgcn_readlane(hv, d));
        }
    }
}

// ---------------------------------------------------------------
// Kernel 3: fold Wc = W1@W2, bc = b1@W2+b2 per k. LDS-staged W2.
// grid 160 x 256. (unchanged from r5)
// ---------------------------------------------------------------
__global__ __launch_bounds__(256) void k_fold(
    const float* __restrict__ W1, const float* __restrict__ b1,
    const float* __restrict__ W2, const float* __restrict__ b2,
    float* __restrict__ Wcg)
{
    const int k = blockIdx.x, t = threadIdx.x;
    __shared__ float sB[12288];   // W2[k], [h][12]
    __shared__ float sb1[1024];
    {
        const float4* w2p = reinterpret_cast<const float4*>(W2 + (size_t)k * 12288);
        float4* sB4 = reinterpret_cast<float4*>(sB);
        for (int i = t; i < 3072; i += 256) sB4[i] = w2p[i];
        const float4* b1p = reinterpret_cast<const float4*>(b1 + (size_t)k * 1024);
        float4* sb14 = reinterpret_cast<float4*>(sb1);
        if (t < 256) sb14[t] = b1p[t];
    }
    __syncthreads();
    if (t >= 156) return;
    const int o = (t < 144) ? (t % 12) : (t - 144);
    float s0 = 0.f, s1 = 0.f, s2 = 0.f, s3 = 0.f;
    if (t < 144) {
        const float4* va4 = reinterpret_cast<const float4*>(W1 + (size_t)k * 12288 + (size_t)(t / 12) * 1024);
        #pragma unroll 4
        for (int q = 0; q < 256; q++) {
            float4 a = va4[q];
            const float* bq = sB + q * 48 + o;
            s0 = fmaf(a.x, bq[0],  s0);
            s1 = fmaf(a.y, bq[12], s1);
            s2 = fmaf(a.z, bq[24], s2);
            s3 = fmaf(a.w, bq[36], s3);
        }
    } else {
        #pragma unroll 4
        for (int hh = 0; hh < 1024; hh += 4) {
            const float* bq = sB + hh * 12 + o;
            s0 = fmaf(sb1[hh],     bq[0],  s0);
            s1 = fmaf(sb1[hh + 1], bq[12], s1);
            s2 = fmaf(sb1[hh + 2], bq[24], s2);
            s3 = fmaf(sb1[hh + 3], bq[36], s3);
        }
    }
    float s = (s0 + s1) + (s2 + s3);
    if (t >= 144) s += b2[k * 12 + o];
    Wcg[k * 156 + t] = s;
}

// ---------------------------------------------------------------
// Kernel 4: apply, in-place on d_out. grid 160 x 256. (unchanged)
// ---------------------------------------------------------------
__global__ __launch_bounds__(256) void k_apply(
    const float* __restrict__ Wcg, float* __restrict__ out)
{
    const int k = blockIdx.x, t = threadIdx.x;
    __shared__ float sw[156];
    if (t < 156) sw[t] = Wcg[k * 156 + t];
    __syncthreads();

    for (int bb = t; bb < 1024; bb += 256) {
        float* hp = out + (size_t)bb * 1920 + k * 12;
        float4* h4 = reinterpret_cast<float4*>(hp);
        float4 a0 = h4[0], a1 = h4[1], a2 = h4[2];
        float hv[12] = {a0.x,a0.y,a0.z,a0.w, a1.x,a1.y,a1.z,a1.w, a2.x,a2.y,a2.z,a2.w};
        float ov[12];
        #pragma unroll
        for (int o = 0; o < 12; o++) {
            float s = sw[144 + o];
            #pragma unroll
            for (int d = 0; d < 12; d++) s = fmaf(hv[d], sw[d * 12 + o], s);
            ov[o] = s;
        }
        h4[0] = make_float4(ov[0], ov[1], ov[2],  ov[3]);
        h4[1] = make_float4(ov[4], ov[5], ov[6],  ov[7]);
        h4[2] = make_float4(ov[8], ov[9], ov[10], ov[11]);
    }
}

// ---------------------------------------------------------------
extern "C" void kernel_launch(void* const* d_in, const int* in_sizes, int n_in,
                              void* d_out, int out_size, void* d_ws, size_t ws_size,
                              hipStream_t stream)
{
    const float* x    = (const float*)d_in[0];
    const float* encW = (const float*)d_in[1];
    const float* encb = (const float*)d_in[2];
    const float* Wih  = (const float*)d_in[3];
    const float* Whh  = (const float*)d_in[4];
    const float* bih  = (const float*)d_in[5];
    const float* bhh  = (const float*)d_in[6];
    const float* W1   = (const float*)d_in[7];
    const float* b1   = (const float*)d_in[8];
    const float* W2   = (const float*)d_in[9];
    const float* b2   = (const float*)d_in[10];
    float* out = (float*)d_out;

    char* ws = (char*)d_ws;
    uint2*  gi   = (uint2*)(ws);
    float4* pegi = (float4*)(ws + OFF_PEGI);
    float*  Wcg  = (float*)(ws + OFF_WC);

    k_encode<<<dim3(4, 160), 256, 0, stream>>>(x, encW, encb, Wih, bih, bhh, gi, pegi);
    k_fold  <<<dim3(160),    256, 0, stream>>>(W1, b1, W2, b2, Wcg);
    k_recur <<<dim3(1024),   64,  0, stream>>>(Whh, bhh, gi, pegi, out);
    k_apply <<<dim3(160),    256, 0, stream>>>(Wcg, out);
}

// Round 8
// 188.331 us; speedup vs baseline: 1.4907x; 1.0764x over previous
//
#include <hip/hip_runtime.h>
#include <hip/hip_bf16.h>

using bf16 = __hip_bfloat16;
typedef float v2f __attribute__((ext_vector_type(2)));

#define C1 1.44269504f   // log2(e)
#define C2 2.88539008f   // 2*log2(e)

__device__ __forceinline__ float fexp2(float x) { return __builtin_amdgcn_exp2f(x); }
__device__ __forceinline__ float frcp(float x)  { return __builtin_amdgcn_rcpf(x); }

__device__ __forceinline__ unsigned int f2bfbits(float f) {  // RNE float->bf16 bits
    union { float f; unsigned int u; } c; c.f = f;
    return (c.u + 0x7fffu + ((c.u >> 16) & 1u)) >> 16;
}

// gi layout: [k][b][12] of uint2 {lo = r|z<<16, hi = n} (bf16 bits, pre-scaled C1/C1/C2)
#define KSTR 12288   // uint2 per k-slice (1024*12)
// ws: gi @0 (15,728,640 B) | pegi float4[160][12] @15,728,640 (30,720 B) => 15.76 MB
#define OFF_PEGI 15728640

// ---------------------------------------------------------------
// Kernel 1: encoder + input-gate precompute. grid (4,160) x 256.
// (unchanged from r5 — proven)
// ---------------------------------------------------------------
__global__ __launch_bounds__(256) void k_encode(
    const float* __restrict__ x, const float* __restrict__ encW, const float* __restrict__ encb,
    const float* __restrict__ Wih, const float* __restrict__ bih, const float* __restrict__ bhh,
    uint2* __restrict__ gi, float4* __restrict__ pegi)
{
    const int k = blockIdx.y, t = threadIdx.x;
    const int b = blockIdx.x * 256 + t;

    __shared__ float sW[144], sbm[12], sWih[432], sbih[36], spet[12];
    __shared__ uint2 st[256 * 13];          // 26 KB staging, stride 13
    if (t < 144) sW[t]  = encW[k * 144 + t];
    if (t < 12)  sbm[t] = encb[k * 12 + t];
    for (int i = t; i < 432; i += 256) sWih[i] = Wih[i];
    if (t < 36)  sbih[t] = bih[t] + (t < 24 ? bhh[t] : 0.f);
    if (t < 12) {
        int m = t >> 1;
        float div = __expf((float)(2 * m) * (-0.7675283643313489f)); // -ln(10000)/12
        float ang = (float)k * div;
        spet[t] = ((t & 1) ? cosf(ang) : sinf(ang)) + sinf((float)k);
    }
    __syncthreads();
    if (t < 12 && blockIdx.x == 0) {
        float sr = 0.f, sz = 0.f, sn = 0.f;
        #pragma unroll
        for (int o = 0; o < 12; o++) {
            sr = fmaf(spet[o], sWih[t * 12 + o], sr);
            sz = fmaf(spet[o], sWih[(12 + t) * 12 + o], sz);
            sn = fmaf(spet[o], sWih[(24 + t) * 12 + o], sn);
        }
        pegi[k * 12 + t] = make_float4(C1 * sr, C1 * sz, C2 * sn, 0.f);
    }

    const float4* xp = reinterpret_cast<const float4*>(x + (size_t)b * 1920 + k * 12);
    float4 a0 = xp[0], a1 = xp[1], a2 = xp[2];
    float xv[12] = {a0.x,a0.y,a0.z,a0.w, a1.x,a1.y,a1.z,a1.w, a2.x,a2.y,a2.z,a2.w};

    float xs[12];
    #pragma unroll
    for (int o = 0; o < 12; o++) {
        float s = sbm[o];
        #pragma unroll
        for (int i = 0; i < 12; i++) s = fmaf(xv[i], sW[i * 12 + o], s);
        xs[o] = fmaxf(s, 0.f);
    }

    #pragma unroll
    for (int j = 0; j < 12; j++) {
        float sr = sbih[j], sz = sbih[12 + j], sn = sbih[24 + j];
        #pragma unroll
        for (int o = 0; o < 12; o++) {
            sr = fmaf(xs[o], sWih[j * 12 + o], sr);
            sz = fmaf(xs[o], sWih[(12 + j) * 12 + o], sz);
            sn = fmaf(xs[o], sWih[(24 + j) * 12 + o], sn);
        }
        st[t * 13 + j] = make_uint2(f2bfbits(C1 * sr) | (f2bfbits(C1 * sz) << 16),
                                    f2bfbits(C2 * sn));
    }
    __syncthreads();
    uint2* gbase = gi + (size_t)k * KSTR + (size_t)blockIdx.x * 3072;
    for (int i = t; i < 3072; i += 256) {
        int bl = i / 12;
        gbase[i] = st[bl * 13 + (i - bl * 12)];
    }
}

// ---------------------------------------------------------------
// Kernel 2: two GRU passes — SGPR-h + packed-pair dots.
// One chain per wave (1024 blocks x 64); lane j<12 owns unit j.
// h broadcast via v_readlane into float2 pairs; dots as v2f FMA
// (v_pk_fma_f32), hn dot first to overlap the trans chain.
// ---------------------------------------------------------------
__global__ __launch_bounds__(64) void k_recur(
    const float* __restrict__ Whh, const float* __restrict__ bhh,
    const uint2* __restrict__ gi, const float4* __restrict__ pegi,
    float* __restrict__ hout)
{
    const int lane = threadIdx.x;
    const int ju = (lane < 12) ? lane : 11;
    const int b = blockIdx.x;

    v2f wr2[6], wz2[6], wn2[6];
    #pragma unroll
    for (int i = 0; i < 6; i++) {
        wr2[i] = (v2f){C1 * Whh[ju * 12 + 2*i],        C1 * Whh[ju * 12 + 2*i + 1]};
        wz2[i] = (v2f){C1 * Whh[(12 + ju) * 12 + 2*i], C1 * Whh[(12 + ju) * 12 + 2*i + 1]};
        wn2[i] = (v2f){C2 * Whh[(24 + ju) * 12 + 2*i], C2 * Whh[(24 + ju) * 12 + 2*i + 1]};
    }
    const float bn = C2 * bhh[24 + ju];

    const uint2* gp = gi + (size_t)b * 12 + ju;

    v2f hs2[6];
    #pragma unroll
    for (int i = 0; i < 6; i++) hs2[i] = (v2f){0.f, 0.f};
    float hself = 0.f, p = 1.f;         // p = 1 - hself

    uint2 buf[8];
    #pragma unroll
    for (int i = 0; i < 8; i++) buf[i] = gp[(size_t)i * KSTR];

    // ---- GRU1 (only final h needed) ----
    for (int ko = 0; ko < 160; ko += 8) {
        #pragma unroll
        for (int i = 0; i < 8; i++) {
            const int k = ko + i;
            const int kp = (k + 8 > 159) ? 159 : k + 8;
            float gr = __int_as_float((int)(buf[i].x << 16));
            float gz = __int_as_float((int)(buf[i].x & 0xffff0000u));
            float gn = __int_as_float((int)(buf[i].y << 16));
            buf[i] = gp[(size_t)kp * KSTR];
            v2f an = (v2f){bn, 0.f};
            v2f ar = (v2f){gr, 0.f};
            v2f az = (v2f){gz, 0.f};
            #pragma unroll
            for (int d = 0; d < 6; d++) an += wn2[d] * hs2[d];   // hn first
            #pragma unroll
            for (int d = 0; d < 6; d++) { ar += wr2[d] * hs2[d]; az += wz2[d] * hs2[d]; }
            float hr = ar.x + ar.y;
            float hz = az.x + az.y;
            float hn = an.x + an.y;
            float r = frcp(1.f + fexp2(-hr));
            float w = frcp(1.f + fexp2(hz));        // 1 - z
            float t = fmaf(r, hn, gn);
            float e = frcp(1.f + fexp2(t));         // n = 1 - 2e
            float hj = fmaf(w, fmaf(-2.f, e, p), hself); // h + w*((1-h) - 2e)
            hself = hj; p = 1.f - hj;
            int hv = __float_as_int(hj);
            #pragma unroll
            for (int d = 0; d < 6; d++)
                hs2[d] = (v2f){__int_as_float(__builtin_amdgcn_readlane(hv, 2*d)),
                               __int_as_float(__builtin_amdgcn_readlane(hv, 2*d + 1))};
        }
    }

    // ---- GRU2 (emit h every step); gi2 = gi1 + pegi[k] ----
    const float4* pp = pegi + ju;
    float4 pb[8];
    #pragma unroll
    for (int i = 0; i < 8; i++) {
        buf[i] = gp[(size_t)i * KSTR];
        pb[i]  = pp[i * 12];
    }
    float* ho = hout + (size_t)b * 1920;            // [b][k][12]
    for (int ko = 0; ko < 160; ko += 8) {
        #pragma unroll
        for (int i = 0; i < 8; i++) {
            const int k = ko + i;
            const int kp = (k + 8 > 159) ? 159 : k + 8;
            float gr = __int_as_float((int)(buf[i].x << 16))         + pb[i].x;
            float gz = __int_as_float((int)(buf[i].x & 0xffff0000u)) + pb[i].y;
            float gn = __int_as_float((int)(buf[i].y << 16))         + pb[i].z;
            buf[i] = gp[(size_t)kp * KSTR];
            pb[i]  = pp[kp * 12];
            v2f an = (v2f){bn, 0.f};
            v2f ar = (v2f){gr, 0.f};
            v2f az = (v2f){gz, 0.f};
            #pragma unroll
            for (int d = 0; d < 6; d++) an += wn2[d] * hs2[d];
            #pragma unroll
            for (int d = 0; d < 6; d++) { ar += wr2[d] * hs2[d]; az += wz2[d] * hs2[d]; }
            float hr = ar.x + ar.y;
            float hz = az.x + az.y;
            float hn = an.x + an.y;
            float r = frcp(1.f + fexp2(-hr));
            float w = frcp(1.f + fexp2(hz));
            float t = fmaf(r, hn, gn);
            float e = frcp(1.f + fexp2(t));
            float hj = fmaf(w, fmaf(-2.f, e, p), hself);
            hself = hj; p = 1.f - hj;
            if (lane < 12) ho[k * 12 + lane] = hj;
            int hv = __float_as_int(hj);
            #pragma unroll
            for (int d = 0; d < 6; d++)
                hs2[d] = (v2f){__int_as_float(__builtin_amdgcn_readlane(hv, 2*d)),
                               __int_as_float(__builtin_amdgcn_readlane(hv, 2*d + 1))};
        }
    }
}

// ---------------------------------------------------------------
// Kernel 3: fold + apply merged. Phase 1: Wc = W1@W2, bc = b1@W2+b2
// into LDS (r5-proven indexing). Phase 2: in-place transform of
// d_out. grid 160 x 256.
// ---------------------------------------------------------------
__global__ __launch_bounds__(256) void k_foldapply(
    const float* __restrict__ W1, const float* __restrict__ b1,
    const float* __restrict__ W2, const float* __restrict__ b2,
    float* __restrict__ out)
{
    const int k = blockIdx.x, t = threadIdx.x;
    __shared__ float sB[12288];   // W2[k], [h][12]
    __shared__ float sb1[1024];
    __shared__ float sWc[144], sbc[12];
    {
        const float4* w2p = reinterpret_cast<const float4*>(W2 + (size_t)k * 12288);
        float4* sB4 = reinterpret_cast<float4*>(sB);
        for (int i = t; i < 3072; i += 256) sB4[i] = w2p[i];
        const float4* b1p = reinterpret_cast<const float4*>(b1 + (size_t)k * 1024);
        float4* sb14 = reinterpret_cast<float4*>(sb1);
        sb14[t] = b1p[t];
    }
    __syncthreads();
    if (t < 156) {
        const int o = (t < 144) ? (t % 12) : (t - 144);
        float s0 = 0.f, s1 = 0.f, s2 = 0.f, s3 = 0.f;
        if (t < 144) {
            const float4* va4 = reinterpret_cast<const float4*>(W1 + (size_t)k * 12288 + (size_t)(t / 12) * 1024);
            #pragma unroll 4
            for (int q = 0; q < 256; q++) {
                float4 a = va4[q];
                const float* bq = sB + q * 48 + o;
                s0 = fmaf(a.x, bq[0],  s0);
                s1 = fmaf(a.y, bq[12], s1);
                s2 = fmaf(a.z, bq[24], s2);
                s3 = fmaf(a.w, bq[36], s3);
            }
        } else {
            #pragma unroll 4
            for (int hh = 0; hh < 1024; hh += 4) {
                const float* bq = sB + hh * 12 + o;
                s0 = fmaf(sb1[hh],     bq[0],  s0);
                s1 = fmaf(sb1[hh + 1], bq[12], s1);
                s2 = fmaf(sb1[hh + 2], bq[24], s2);
                s3 = fmaf(sb1[hh + 3], bq[36], s3);
            }
        }
        float s = (s0 + s1) + (s2 + s3);
        if (t < 144) sWc[t] = s;
        else         sbc[t - 144] = s + b2[k * 12 + o];
    }
    __syncthreads();

    for (int bb = t; bb < 1024; bb += 256) {
        float* hp = out + (size_t)bb * 1920 + k * 12;
        float4* h4 = reinterpret_cast<float4*>(hp);
        float4 a0 = h4[0], a1 = h4[1], a2 = h4[2];
        float hv[12] = {a0.x,a0.y,a0.z,a0.w, a1.x,a1.y,a1.z,a1.w, a2.x,a2.y,a2.z,a2.w};
        float ov[12];
        #pragma unroll
        for (int o = 0; o < 12; o++) {
            float s = sbc[o];
            #pragma unroll
            for (int d = 0; d < 12; d++) s = fmaf(hv[d], sWc[d * 12 + o], s);
            ov[o] = s;
        }
        h4[0] = make_float4(ov[0], ov[1], ov[2],  ov[3]);
        h4[1] = make_float4(ov[4], ov[5], ov[6],  ov[7]);
        h4[2] = make_float4(ov[8], ov[9], ov[10], ov[11]);
    }
}

// ---------------------------------------------------------------
extern "C" void kernel_launch(void* const* d_in, const int* in_sizes, int n_in,
                              void* d_out, int out_size, void* d_ws, size_t ws_size,
                              hipStream_t stream)
{
    const float* x    = (const float*)d_in[0];
    const float* encW = (const float*)d_in[1];
    const float* encb = (const float*)d_in[2];
    const float* Wih  = (const float*)d_in[3];
    const float* Whh  = (const float*)d_in[4];
    const float* bih  = (const float*)d_in[5];
    const float* bhh  = (const float*)d_in[6];
    const float* W1   = (const float*)d_in[7];
    const float* b1   = (const float*)d_in[8];
    const float* W2   = (const float*)d_in[9];
    const float* b2   = (const float*)d_in[10];
    float* out = (float*)d_out;

    char* ws = (char*)d_ws;
    uint2*  gi   = (uint2*)(ws);
    float4* pegi = (float4*)(ws + OFF_PEGI);

    k_encode   <<<dim3(4, 160), 256, 0, stream>>>(x, encW, encb, Wih, bih, bhh, gi, pegi);
    k_recur    <<<dim3(1024),   64,  0, stream>>>(Whh, bhh, gi, pegi, out);
    k_foldapply<<<dim3(160),    256, 0, stream>>>(W1, b1, W2, b2, out);
}